// Round 15
// baseline (62.078 us; speedup 1.0000x reference)
//
#include <hip/hip_runtime.h>

#define N_EMB   8192
#define D_EMB   128
#define NSTEPS  201
#define NB      128                  // 8192 / 64 tiles per dim
#define TBLOCKS (NB*(NB+1)/2)        // 8256 upper-tri tiles incl. diagonal
#define NCOPY   16                   // replicated global histogram copies
#define NHIST   16                   // per-quarter-wave LDS copies (per sign table)
#define PGRID   1536                 // persistent grid (6 blocks/CU, LDS-limited)

typedef __attribute__((ext_vector_type(4))) int i32x4;

// packed per-bin accumulator: (count << 21) | fq, fq = round(frac*1024)
#define CNT_SHIFT  21
#define FRAC_MASK  ((1u << CNT_SHIFT) - 1u)
#define NZERO      (NCOPY * 2 * NSTEPS)      // floats to zero in ghist

// ---- pre-pass: fp32 -> int8 fragment-tiled (per-row scale); zeroes ghist+ticket ----
__global__ __launch_bounds__(256) void convert_kernel(
    const float* __restrict__ x1, const float* __restrict__ x2,
    signed char* __restrict__ x1q, signed char* __restrict__ x2q,
    float* __restrict__ sc1, float* __restrict__ sc2,
    float* __restrict__ ghist, unsigned int* __restrict__ gdone)
{
  int t = blockIdx.x * 256 + threadIdx.x;        // 0 .. 262143
  if (t < NZERO) ghist[t] = 0.0f;
  if (t == 0)    gdone[0] = 0u;
  const bool first = (t < 131072);
  const float* src = first ? x1  : x2;
  signed char* dst = first ? x1q : x2q;
  float*       scd = first ? sc1 : sc2;
  int tt  = t & 131071;
  int r   = tt >> 4;                             // row 0..8191
  int c16 = tt & 15;                             // 8-elem chunk within row
  const float4* g = reinterpret_cast<const float4*>(src + ((size_t)r << 7) + c16*8);
  float4 v0 = g[0], v1 = g[1];

  // row max-abs via 16-lane butterfly (threads of one row are lane-contiguous)
  float m = fmaxf(fmaxf(fmaxf(fabsf(v0.x), fabsf(v0.y)), fmaxf(fabsf(v0.z), fabsf(v0.w))),
                  fmaxf(fmaxf(fabsf(v1.x), fabsf(v1.y)), fmaxf(fabsf(v1.z), fabsf(v1.w))));
#pragma unroll
  for (int d = 1; d < 16; d <<= 1) m = fmaxf(m, __shfl_xor(m, d, 16));

  float qs = 127.0f / m;
  int q0 = (int)rintf(v0.x * qs), q1 = (int)rintf(v0.y * qs);
  int q2 = (int)rintf(v0.z * qs), q3 = (int)rintf(v0.w * qs);
  int q4 = (int)rintf(v1.x * qs), q5 = (int)rintf(v1.y * qs);
  int q6 = (int)rintf(v1.z * qs), q7 = (int)rintf(v1.w * qs);
  uint2 pk;
  pk.x = (q0 & 255) | ((q1 & 255) << 8) | ((q2 & 255) << 16) | ((unsigned)(q3 & 255) << 24);
  pk.y = (q4 & 255) | ((q5 & 255) << 8) | ((q6 & 255) << 16) | ((unsigned)(q7 & 255) << 24);

  int R = r >> 4, fr = r & 15;
  size_t chunk = ((size_t)(R*2 + (c16 >> 3)) << 6) + (size_t)(((c16 >> 1) & 3)*16 + fr);
  *reinterpret_cast<uint2*>(dst + chunk*16 + (c16 & 1)*8) = pk;

  if (c16 == 0) scd[r] = m * (1.0f / 127.0f);
}

// ============ main: i8 MFMA, pipelined deposits, ticket-fused finalize ============
__global__ __launch_bounds__(256, 6) void main_kernel(
    const signed char* __restrict__ x1q, const signed char* __restrict__ x2q,
    const float* __restrict__ sc1g, const float* __restrict__ sc2g,
    const float* __restrict__ t1g, const float* __restrict__ t2g,
    float* __restrict__ ghist, unsigned int* __restrict__ gdone,
    float* __restrict__ out)
{
  __shared__ unsigned int whist[2][NHIST][NSTEPS];   // [pos/neg][copy][bin]
  __shared__ int lastFlag;

  const int tid = threadIdx.x;
  for (int b = tid; b < 2*NHIST*NSTEPS; b += 256) ((unsigned int*)whist)[b] = 0u;

  const int lane = tid & 63;
  const int w    = tid >> 6;
  const int wr   = w >> 1, wc = w & 1;
  const int fr   = lane & 15;
  const int kg   = lane >> 4;
  const int rbase = kg * 4;
  unsigned int* whP = &whist[0][(w << 2) | kg][0];
  const int NEGOFF = NHIST * NSTEPS;

  // static strict-upper mask for diagonal tiles: bit k=(tm*2+tn)*4+rr
  unsigned upmask = 0;
#pragma unroll
  for (int tm = 0; tm < 2; ++tm)
#pragma unroll
    for (int tn = 0; tn < 2; ++tn)
#pragma unroll
      for (int rr = 0; rr < 4; ++rr) {
        int li = wr*32 + tm*16 + rbase + rr;
        int lj = wc*32 + tn*16 + fr;
        if (lj > li) upmask |= 1u << ((tm*2 + tn)*4 + rr);
      }

  const i32x4* Aq = reinterpret_cast<const i32x4*>(x1q);
  const i32x4* Bq = reinterpret_cast<const i32x4*>(x2q);

  // XCD-aware swizzle (bijective: 1536 = 8 XCDs * 192)
  const unsigned bid = ((unsigned)blockIdx.x & 7u) * 192u + ((unsigned)blockIdx.x >> 3);
  const int t0  = (int)((bid      * 43u) >> 3);
  const int t1e = (int)(((bid+1u) * 43u) >> 3);

  __syncthreads();                            // whist zeroing visible

  // decode starting strip
  int j = (int)((sqrtf(8.0f*(float)t0 + 1.0f) - 1.0f) * 0.5f);
  while ((j+1)*(j+2)/2 <= t0) ++j;
  while (j*(j+1)/2 > t0) --j;
  int bi = t0 - j*(j+1)/2;

  int t = t0;
  while (t < t1e) {
    // ---- strip j setup: B frags + col targets/scales ----
    const int gj0 = j*64;
    const int Rb = (gj0 >> 4) + wc*2;
    i32x4 bQ00 = Bq[((size_t)(Rb    *2 + 0) << 6) + lane];
    i32x4 bQ01 = Bq[((size_t)(Rb    *2 + 1) << 6) + lane];
    i32x4 bQ10 = Bq[((size_t)((Rb+1)*2 + 0) << 6) + lane];
    i32x4 bQ11 = Bq[((size_t)((Rb+1)*2 + 1) << 6) + lane];
    float T1v0 = t1g[gj0 + wc*32 + fr];
    float T1v1 = t1g[gj0 + wc*32 + 16 + fr];
    float sB0  = sc2g[gj0 + wc*32 + fr];
    float sB1  = sc2g[gj0 + wc*32 + 16 + fr];

    const int cnt = min(j + 1 - bi, t1e - t);
    const int bi_end = bi + cnt;

    // pipelined inner loop: deposits of tile bi-1 run under loads of tile bi
    float    pSu[2][2][4];                    // prev scaled sims [tm][tn][rr]
    unsigned pPos0 = 0, pPos1 = 0;            // prev sign masks (bit tm*4+rr)
    unsigned pFull = 0;
    bool havePrev = false;

    auto DEP = [&]() {
#pragma unroll
      for (int tm = 0; tm < 2; ++tm)
#pragma unroll
        for (int tn = 0; tn < 2; ++tn)
#pragma unroll
          for (int rr = 0; rr < 4; ++rr) {
            float uu = pSu[tm][tn][rr] + 102400.5f;
            int   iu = (int)uu;
            int  idx = iu >> 10;
            idx = idx < 0 ? 0 : (idx > NSTEPS-1 ? NSTEPS-1 : idx);
            unsigned pk = (1u << CNT_SHIFT) | (unsigned)(iu & 1023);
            unsigned pb = tn ? pPos1 : pPos0;
            unsigned off = ((pb >> (tm*4 + rr)) & 1u) ? 0u : (unsigned)NEGOFF;
            bool take = pFull || ((upmask >> ((tm*2 + tn)*4 + rr)) & 1u);
            if (take) atomicAdd(whP + off + idx, pk);
          }
    };

    for (; bi < bi_end; ++bi, ++t) {
      const int gi0 = bi*64;
      const int Ra = (gi0 >> 4) + wr*2;
      // issue A-frag loads
      i32x4 a00 = Aq[((size_t)(Ra    *2 + 0) << 6) + lane];
      i32x4 a01 = Aq[((size_t)(Ra    *2 + 1) << 6) + lane];
      i32x4 a10 = Aq[((size_t)((Ra+1)*2 + 0) << 6) + lane];
      i32x4 a11 = Aq[((size_t)((Ra+1)*2 + 1) << 6) + lane];
      // row targets -> sign masks immediately; scales premultiplied
      float sAv[2][4];
      unsigned cPos0 = 0, cPos1 = 0;
#pragma unroll
      for (int tm = 0; tm < 2; ++tm)
#pragma unroll
        for (int rr = 0; rr < 4; ++rr) {
          int gi = gi0 + wr*32 + tm*16 + rbase + rr;
          float t2 = t2g[gi];
          sAv[tm][rr] = sc1g[gi] * 102400.0f;
          cPos0 |= (t2 * T1v0 > 0.0f ? 1u : 0u) << (tm*4 + rr);
          cPos1 |= (t2 * T1v1 > 0.0f ? 1u : 0u) << (tm*4 + rr);
        }

      // deposits of previous tile (hide current loads' latency)
      if (havePrev) DEP();

      // MFMA (waits on a-loads)
      i32x4 acc00 = {0,0,0,0}, acc01 = {0,0,0,0};
      i32x4 acc10 = {0,0,0,0}, acc11 = {0,0,0,0};
      acc00 = __builtin_amdgcn_mfma_i32_16x16x64_i8(a00, bQ00, acc00, 0, 0, 0);
      acc00 = __builtin_amdgcn_mfma_i32_16x16x64_i8(a01, bQ01, acc00, 0, 0, 0);
      acc01 = __builtin_amdgcn_mfma_i32_16x16x64_i8(a00, bQ10, acc01, 0, 0, 0);
      acc01 = __builtin_amdgcn_mfma_i32_16x16x64_i8(a01, bQ11, acc01, 0, 0, 0);
      acc10 = __builtin_amdgcn_mfma_i32_16x16x64_i8(a10, bQ00, acc10, 0, 0, 0);
      acc10 = __builtin_amdgcn_mfma_i32_16x16x64_i8(a11, bQ01, acc10, 0, 0, 0);
      acc11 = __builtin_amdgcn_mfma_i32_16x16x64_i8(a10, bQ10, acc11, 0, 0, 0);
      acc11 = __builtin_amdgcn_mfma_i32_16x16x64_i8(a11, bQ11, acc11, 0, 0, 0);

      // fold scales into prev state (C/D layout m89/m91: col=lane&15, row=(lane>>4)*4+reg)
#pragma unroll
      for (int rr = 0; rr < 4; ++rr) {
        pSu[0][0][rr] = (float)acc00[rr] * (sAv[0][rr] * sB0);
        pSu[0][1][rr] = (float)acc01[rr] * (sAv[0][rr] * sB1);
        pSu[1][0][rr] = (float)acc10[rr] * (sAv[1][rr] * sB0);
        pSu[1][1][rr] = (float)acc11[rr] * (sAv[1][rr] * sB1);
      }
      pPos0 = cPos0; pPos1 = cPos1;
      pFull = (bi != j) ? 1u : 0u;
      havePrev = true;
    }
    if (havePrev) DEP();                      // strip epilogue
    bi = 0; ++j;                              // next strip
  }
  __syncthreads();

  // unpack + flush once per sign table:
  // h[b] = cnt[b] - fr[b]/1024 + fr[b-1]/1024 ; h[200] = cnt[200] + fr[199]/1024
  float* gh = ghist + (size_t)(blockIdx.x & (NCOPY-1)) * (2*NSTEPS);
  if (tid < NSTEPS) {
    const int b = tid;
    const float inv = 1.0f / 1024.0f;
#pragma unroll
    for (int sg = 0; sg < 2; ++sg) {
      unsigned int cp = 0; float fp = 0.f, fpm1 = 0.f;
#pragma unroll
      for (int ww = 0; ww < NHIST; ++ww) {
        unsigned int vp = whist[sg][ww][b];
        cp += vp >> CNT_SHIFT;  fp += (float)(vp & FRAC_MASK);
        if (b > 0) fpm1 += (float)(whist[sg][ww][b-1] & FRAC_MASK);
      }
      float hv = (b == NSTEPS-1) ? ((float)cp + fpm1 * inv)
                                 : ((float)cp - fp * inv + fpm1 * inv);
      if (hv != 0.0f) atomicAdd(&gh[sg*NSTEPS + b], hv);
    }
  }

  // ---- ticket: last block finalizes (result independent of which block) ----
  if (tid == 0) {
    __threadfence();
    unsigned prev = atomicAdd(gdone, 1u);
    lastFlag = (prev == (unsigned)(PGRID - 1));
  }
  __syncthreads();
  if (lastFlag) {
    float* hf = (float*)&whist[0][0][0];      // reuse LDS (whist consumed)
    if (tid < NSTEPS) {
      float sp = 0.f, sn = 0.f;
#pragma unroll
      for (int c = 0; c < NCOPY; ++c) {       // coherent reads via atomic-add-zero
        sp += atomicAdd(&ghist[(size_t)c*(2*NSTEPS) + tid], 0.0f);
        sn += atomicAdd(&ghist[(size_t)c*(2*NSTEPS) + NSTEPS + tid], 0.0f);
      }
      hf[tid] = sp; hf[NSTEPS + tid] = sn;
    }
    __syncthreads();
    if (tid == 0) {
      const float TOT = 33550336.0f;          // N*(N-1)/2
      float np = 0.f;
      for (int b = 0; b < NSTEPS; ++b) np += hf[b];
      float nn = TOT - np;
      float ip  = 1.0f / fmaxf(np, 1.0f);
      float in_ = 1.0f / fmaxf(nn, 1.0f);
      float cdf = 0.f, loss = 0.f;
      for (int b = 0; b < NSTEPS; ++b) {
        cdf  += hf[b] * ip;
        loss += hf[NSTEPS + b] * in_ * cdf;
      }
      out[0] = loss;
    }
  }
}

extern "C" void kernel_launch(void* const* d_in, const int* in_sizes, int n_in,
                              void* d_out, int out_size, void* d_ws, size_t ws_size,
                              hipStream_t stream) {
  const float* x1 = (const float*)d_in[0];
  const float* x2 = (const float*)d_in[1];
  const float* t1 = (const float*)d_in[2];
  const float* t2 = (const float*)d_in[3];
  float* out = (float*)d_out;

  const size_t Q_BYTES = (size_t)N_EMB * D_EMB;          // 1 MB each (i8)
  const size_t S_BYTES = (size_t)N_EMB * sizeof(float);  // 32 KB each
  char* p = (char*)d_ws;
  signed char* x1q   = (signed char*)p;   p += Q_BYTES;
  signed char* x2q   = (signed char*)p;   p += Q_BYTES;
  float*       sc1   = (float*)p;         p += S_BYTES;
  float*       sc2   = (float*)p;         p += S_BYTES;
  float*       ghist = (float*)p;         p += (size_t)NZERO*sizeof(float);
  unsigned int* gdone = (unsigned int*)p;

  convert_kernel<<<(2*N_EMB*D_EMB/8 + 255)/256, 256, 0, stream>>>(x1, x2, x1q, x2q, sc1, sc2, ghist, gdone);
  main_kernel<<<PGRID, 256, 0, stream>>>(x1q, x2q, sc1, sc2, t1, t2, ghist, gdone, out);
}

// Round 16
// 39.166 us; speedup vs baseline: 1.5850x; 1.5850x over previous
//
#include <hip/hip_runtime.h>

#define N_EMB   8192
#define D_EMB   128
#define NSTEPS  201
#define NB      128                  // 8192 / 64 tiles per dim
#define TBLOCKS (NB*(NB+1)/2)        // 8256 upper-tri tiles incl. diagonal
#define NCOPY   16                   // replicated global histogram copies
#define NHIST   16                   // per-quarter-wave LDS copies (per sign table)
#define PGRID   1536                 // persistent grid (6 blocks/CU, LDS-limited)

typedef __attribute__((ext_vector_type(4))) int i32x4;

// packed per-bin accumulator: (count << 21) | fq, fq = round(frac*1024)
#define CNT_SHIFT  21
#define FRAC_MASK  ((1u << CNT_SHIFT) - 1u)
#define NZERO      (NCOPY * 2 * NSTEPS)      // floats to zero in ghist

// ---- pre-pass: fp32 -> int8 fragment-tiled; per-row meta {scale, target}; zero ghist ----
// i8 16x16x64 fragment: lane l holds row (l&15), k = (l>>4)*16 + [0..15] (16 B).
__global__ __launch_bounds__(256) void convert_kernel(
    const float* __restrict__ x1, const float* __restrict__ x2,
    const float* __restrict__ t1, const float* __restrict__ t2,
    signed char* __restrict__ x1q, signed char* __restrict__ x2q,
    float2* __restrict__ meta1, float2* __restrict__ meta2,
    float* __restrict__ ghist)
{
  int t = blockIdx.x * 256 + threadIdx.x;        // 0 .. 262143
  if (t < NZERO) ghist[t] = 0.0f;
  const bool first = (t < 131072);
  const float* src = first ? x1  : x2;
  signed char* dst = first ? x1q : x2q;
  int tt  = t & 131071;
  int r   = tt >> 4;                             // row 0..8191
  int c16 = tt & 15;                             // 8-elem chunk within row
  const float4* g = reinterpret_cast<const float4*>(src + ((size_t)r << 7) + c16*8);
  float4 v0 = g[0], v1 = g[1];

  // row max-abs via 16-lane butterfly (threads of one row are lane-contiguous)
  float m = fmaxf(fmaxf(fmaxf(fabsf(v0.x), fabsf(v0.y)), fmaxf(fabsf(v0.z), fabsf(v0.w))),
                  fmaxf(fmaxf(fabsf(v1.x), fabsf(v1.y)), fmaxf(fabsf(v1.z), fabsf(v1.w))));
#pragma unroll
  for (int d = 1; d < 16; d <<= 1) m = fmaxf(m, __shfl_xor(m, d, 16));

  float qs = 127.0f / m;
  int q0 = (int)rintf(v0.x * qs), q1 = (int)rintf(v0.y * qs);
  int q2 = (int)rintf(v0.z * qs), q3 = (int)rintf(v0.w * qs);
  int q4 = (int)rintf(v1.x * qs), q5 = (int)rintf(v1.y * qs);
  int q6 = (int)rintf(v1.z * qs), q7 = (int)rintf(v1.w * qs);
  uint2 pk;
  pk.x = (q0 & 255) | ((q1 & 255) << 8) | ((q2 & 255) << 16) | ((unsigned)(q3 & 255) << 24);
  pk.y = (q4 & 255) | ((q5 & 255) << 8) | ((q6 & 255) << 16) | ((unsigned)(q7 & 255) << 24);

  int R = r >> 4, fr = r & 15;
  size_t chunk = ((size_t)(R*2 + (c16 >> 3)) << 6) + (size_t)(((c16 >> 1) & 3)*16 + fr);
  *reinterpret_cast<uint2*>(dst + chunk*16 + (c16 & 1)*8) = pk;

  if (c16 == 0) {
    if (first) meta1[r] = make_float2(m * (102400.0f / 127.0f), t2[r]);   // {scA*102400, t2}
    else       meta2[r] = make_float2(m * (1.0f / 127.0f),      t1[r]);   // {scB, t1}
  }
}

// ============ main pass: both histograms, persistent, nested strip loops, i8 MFMA ============
__global__ __launch_bounds__(256, 6) void main_kernel(
    const signed char* __restrict__ x1q, const signed char* __restrict__ x2q,
    const float2* __restrict__ meta1g, const float2* __restrict__ meta2g,
    float* __restrict__ ghist)
{
  __shared__ unsigned int whist[2][NHIST][NSTEPS];   // [pos/neg][copy][bin]

  const int tid = threadIdx.x;
  for (int b = tid; b < 2*NHIST*NSTEPS; b += 256) ((unsigned int*)whist)[b] = 0u;

  const int lane = tid & 63;
  const int w    = tid >> 6;
  const int wr   = w >> 1, wc = w & 1;
  const int fr   = lane & 15;
  const int kg   = lane >> 4;
  const int rbase = kg * 4;
  unsigned int* whP = &whist[0][(w << 2) | kg][0];
  const int NEGOFF = NHIST * NSTEPS;          // element offset pos-table -> neg-table

  const i32x4* A = reinterpret_cast<const i32x4*>(x1q);
  const i32x4* B = reinterpret_cast<const i32x4*>(x2q);

  // XCD-aware swizzle (bijective: 1536 = 8 XCDs * 192)
  const unsigned bid = ((unsigned)blockIdx.x & 7u) * 192u + ((unsigned)blockIdx.x >> 3);
  const int t0  = (int)((bid      * 43u) >> 3);
  const int t1e = (int)(((bid+1u) * 43u) >> 3);

  __syncthreads();                            // whist zeroing visible

  // decode starting strip once
  int j = (int)((sqrtf(8.0f*(float)t0 + 1.0f) - 1.0f) * 0.5f);
  while ((j+1)*(j+2)/2 <= t0) ++j;
  while (j*(j+1)/2 > t0) --j;
  int bi = t0 - j*(j+1)/2;

  int t = t0;
  while (t < t1e) {
    // ---- strip j: load B frags + col meta (outer loop) ----
    const int gj0 = j*64;
    const int Rb = (gj0 >> 4) + wc*2;
    i32x4 bQ[2][2];
#pragma unroll
    for (int ks = 0; ks < 2; ++ks) {
      bQ[0][ks] = B[((size_t)(Rb    *2 + ks) << 6) + lane];
      bQ[1][ks] = B[((size_t)((Rb+1)*2 + ks) << 6) + lane];
    }
    float2 mB0 = meta2g[gj0 + wc*32 + fr];         // {sB, t1}
    float2 mB1 = meta2g[gj0 + wc*32 + 16 + fr];

    const int cnt = min(j + 1 - bi, t1e - t);
    const int bi_end = bi + cnt;

    // ---- inner loop over rows of the strip ----
    for (; bi < bi_end; ++bi) {
      const int gi0 = bi*64;
      const bool full = (bi != j);
      const int Ra = (gi0 >> 4) + wr*2;

      // row meta early (independent of MFMA): {scA*102400, t2}
      float2 mA[2][4];
#pragma unroll
      for (int tm = 0; tm < 2; ++tm)
#pragma unroll
        for (int rr = 0; rr < 4; ++rr)
          mA[tm][rr] = meta1g[gi0 + wr*32 + tm*16 + rbase + rr];

      i32x4 acc00 = {0,0,0,0}, acc01 = {0,0,0,0};
      i32x4 acc10 = {0,0,0,0}, acc11 = {0,0,0,0};
#pragma unroll
      for (int ks = 0; ks < 2; ++ks) {
        i32x4 a0 = A[((size_t)(Ra    *2 + ks) << 6) + lane];
        i32x4 a1 = A[((size_t)((Ra+1)*2 + ks) << 6) + lane];
        acc00 = __builtin_amdgcn_mfma_i32_16x16x64_i8(a0, bQ[0][ks], acc00, 0, 0, 0);
        acc01 = __builtin_amdgcn_mfma_i32_16x16x64_i8(a0, bQ[1][ks], acc01, 0, 0, 0);
        acc10 = __builtin_amdgcn_mfma_i32_16x16x64_i8(a1, bQ[0][ks], acc10, 0, 0, 0);
        acc11 = __builtin_amdgcn_mfma_i32_16x16x64_i8(a1, bQ[1][ks], acc11, 0, 0, 0);
      }

      // C/D layout (m89/m91, shape-determined): col = lane&15, row = (lane>>4)*4 + reg
      auto dep = [&](const i32x4& a, int tm, const float2& mB, int tn) {
        const int lj = wc*32 + tn*16 + fr;
#pragma unroll
        for (int rr = 0; rr < 4; ++rr) {
          const int li = wr*32 + tm*16 + rbase + rr;
          bool pos = (mA[tm][rr].y * mB.y > 0.0f);
          // s = ia * sA*sB ; uu = s*102400 + 102400.5 (scale folded)
          float uu = fmaf((float)a[rr], mA[tm][rr].x * mB.x, 102400.5f);
          int   iu = (int)uu;
          int  idx = iu >> 10;
          idx = idx < 0 ? 0 : (idx > NSTEPS-1 ? NSTEPS-1 : idx);
          unsigned int pkv = (1u << CNT_SHIFT) | (unsigned int)(iu & 1023);
          unsigned int* dst = whP + (pos ? 0 : NEGOFF) + idx;
          if (full || (lj > li)) atomicAdd(dst, pkv);
        }
      };
      dep(acc00, 0, mB0, 0); dep(acc01, 0, mB1, 1);
      dep(acc10, 1, mB0, 0); dep(acc11, 1, mB1, 1);
      ++t;
    }
    bi = 0; ++j;                              // next strip
  }
  __syncthreads();

  // unpack + flush once per sign table:
  // h[b] = cnt[b] - fr[b]/1024 + fr[b-1]/1024 ; h[200] = cnt[200] + fr[199]/1024
  float* gh = ghist + (size_t)(blockIdx.x & (NCOPY-1)) * (2*NSTEPS);
  if (tid < NSTEPS) {
    const int b = tid;
    const float inv = 1.0f / 1024.0f;
#pragma unroll
    for (int sg = 0; sg < 2; ++sg) {
      unsigned int cp = 0; float fp = 0.f, fpm1 = 0.f;
#pragma unroll
      for (int ww = 0; ww < NHIST; ++ww) {
        unsigned int vp = whist[sg][ww][b];
        cp += vp >> CNT_SHIFT;  fp += (float)(vp & FRAC_MASK);
        if (b > 0) fpm1 += (float)(whist[sg][ww][b-1] & FRAC_MASK);
      }
      float hv = (b == NSTEPS-1) ? ((float)cp + fpm1 * inv)
                                 : ((float)cp - fp * inv + fpm1 * inv);
      if (hv != 0.0f) atomicAdd(&gh[sg*NSTEPS + b], hv);
    }
  }
}

// ============ finalize: sum copies, cumsum pos, dot with neg ============
__global__ void finalize_kernel(const float* __restrict__ ghist,
                                float* __restrict__ out)
{
  __shared__ float hp[NSTEPS], hn[NSTEPS];
  const int tid = threadIdx.x;
  if (tid < NSTEPS) {
    float sp = 0.f, sn = 0.f;
#pragma unroll
    for (int c = 0; c < NCOPY; ++c) {
      sp += ghist[(size_t)c*(2*NSTEPS) + tid];
      sn += ghist[(size_t)c*(2*NSTEPS) + NSTEPS + tid];
    }
    hp[tid] = sp; hn[tid] = sn;
  }
  __syncthreads();
  if (tid == 0) {
    const float TOT = 33550336.0f;            // N*(N-1)/2
    float np = 0.f;
    for (int b = 0; b < NSTEPS; ++b) np += hp[b];
    float nn = TOT - np;
    float ip  = 1.0f / fmaxf(np, 1.0f);
    float in_ = 1.0f / fmaxf(nn, 1.0f);
    float cdf = 0.f, loss = 0.f;
    for (int b = 0; b < NSTEPS; ++b) {
      cdf  += hp[b] * ip;
      loss += hn[b] * in_ * cdf;
    }
    out[0] = loss;
  }
}

extern "C" void kernel_launch(void* const* d_in, const int* in_sizes, int n_in,
                              void* d_out, int out_size, void* d_ws, size_t ws_size,
                              hipStream_t stream) {
  const float* x1 = (const float*)d_in[0];
  const float* x2 = (const float*)d_in[1];
  const float* t1 = (const float*)d_in[2];
  const float* t2 = (const float*)d_in[3];
  float* out = (float*)d_out;

  const size_t Q_BYTES = (size_t)N_EMB * D_EMB;           // 1 MB each (i8)
  const size_t M_BYTES = (size_t)N_EMB * sizeof(float2);  // 64 KB each
  char* p = (char*)d_ws;
  signed char* x1q   = (signed char*)p;   p += Q_BYTES;
  signed char* x2q   = (signed char*)p;   p += Q_BYTES;
  float2*      meta1 = (float2*)p;        p += M_BYTES;
  float2*      meta2 = (float2*)p;        p += M_BYTES;
  float*       ghist = (float*)p;

  convert_kernel<<<(2*N_EMB*D_EMB/8 + 255)/256, 256, 0, stream>>>(x1, x2, t1, t2, x1q, x2q, meta1, meta2, ghist);
  main_kernel<<<PGRID, 256, 0, stream>>>(x1q, x2q, meta1, meta2, ghist);
  finalize_kernel<<<1, 256, 0, stream>>>(ghist, out);
}